// Round 6
// baseline (385.413 us; speedup 1.0000x reference)
//
#include <hip/hip_runtime.h>

// Problem constants
static constexpr int   Cc  = 21;
static constexpr int   HWn = 512 * 512;         // 262144 = 2^18
static constexpr int   Nn  = 8 * HWn;           // 2097152 pixels
static constexpr float MAXM  = 0.5f;
static constexpr float Sc    = 30.0f;
static constexpr float LOG2E = 1.4426950408889634f;
static constexpr float LN2   = 0.6931471805599453f;

// ws layout (bytes), all zeroed by one 256-B memsetAsync:
//   0   : int    counts[21]
//   88  : int    hist_done
//   92  : int    loss_done
//   96  : double acc
//   112 : float  sm2[21]   (= S * m_list[c] * LOG2E)
static constexpr int WS_COUNTS    = 0;
static constexpr int WS_HIST_DONE = 88;
static constexpr int WS_LOSS_DONE = 92;
static constexpr int WS_ACC       = 96;
static constexpr int WS_SM        = 112;

// ---------------------------------------------------------------------------
// K1: class histogram (8 labels/thread, two coalesced int4 streams, per-wave
// LDS sub-histograms) + fused m_list: the last block to finish computes
// sm2[c] = S*LOG2E * m_list[c] from the global counts.
__global__ __launch_bounds__(256) void hist_kernel(const int4* __restrict__ t4,
                                                   int* __restrict__ counts,
                                                   int* __restrict__ hist_done,
                                                   float* __restrict__ sm2) {
    __shared__ int lh[4][Cc];                 // per-wave sub-histograms
    __shared__ int is_last;
    int t    = threadIdx.x;
    int wave = t >> 6;
    if (t < Cc) { lh[0][t] = 0; lh[1][t] = 0; lh[2][t] = 0; lh[3][t] = 0; }
    __syncthreads();

    int tid = blockIdx.x * 256 + t;           // [0, Nn/8)
    int4 a = t4[tid];                         // first half of label array
    int4 b = t4[tid + (Nn / 8)];              // second half
    atomicAdd(&lh[wave][a.x], 1);
    atomicAdd(&lh[wave][a.y], 1);
    atomicAdd(&lh[wave][a.z], 1);
    atomicAdd(&lh[wave][a.w], 1);
    atomicAdd(&lh[wave][b.x], 1);
    atomicAdd(&lh[wave][b.y], 1);
    atomicAdd(&lh[wave][b.z], 1);
    atomicAdd(&lh[wave][b.w], 1);
    __syncthreads();
    if (t < Cc) atomicAdd(&counts[t], lh[0][t] + lh[1][t] + lh[2][t] + lh[3][t]);
    __syncthreads();                          // drains the count atomics (vmcnt)

    if (t == 0) {
        __threadfence();                      // release: counts visible first
        int prev = atomicAdd(hist_done, 1);
        is_last = (prev == (int)gridDim.x - 1);
    }
    __syncthreads();

    if (is_last && t < 64) {                  // fused mlist on one wave
        __threadfence();                      // acquire
        float mval = 0.0f;
        if (t < Cc) {
            int cnt = atomicAdd(&counts[t], 0);   // device-scope atomic read
            mval = 1.0f / sqrtf(sqrtf((float)cnt + 1e-4f));
        }
        float mx = mval;
        #pragma unroll
        for (int o = 32; o >= 1; o >>= 1) mx = fmaxf(mx, __shfl_down(mx, o));
        mx = __shfl(mx, 0);
        if (t < Cc) sm2[t] = Sc * LOG2E * mval * (MAXM / mx);
    }
}

// ---------------------------------------------------------------------------
// K2: main loss + fused finalize. FOUR pixels/thread via float4 loads across
// the 21-class stride; x[21] register-resident (84 data VGPRs); pass 2
// recomputes margin-adjusted values from x (no second array -> no spill).
// Softmax in base-2 domain (exp2/log2), single *LN2 at the end.
// Last block to finish writes mean to out.
__global__ __launch_bounds__(256, 2) void loss_kernel(const float* __restrict__ pred,
                                                      const int4* __restrict__ t4,
                                                      const float* __restrict__ smg,
                                                      double* __restrict__ acc,
                                                      int* __restrict__ loss_done,
                                                      float* __restrict__ out) {
    __shared__ float s_sm[Cc];
    __shared__ float wsum[4];
    int t = threadIdx.x;
    if (t < Cc) s_sm[t] = smg[t];
    __syncthreads();

    int tid = blockIdx.x * 256 + t;           // [0, Nn/4)
    int n0  = tid * 4;
    int b   = n0 >> 18;                       // HWn = 2^18
    int hw  = n0 & (HWn - 1);
    const float4* p4 = (const float4*)(pred + (size_t)b * Cc * HWn + hw);

    // issue all 21 coalesced float4 loads back-to-back (MLP)
    float4 x[Cc];
    #pragma unroll
    for (int c = 0; c < Cc; ++c) x[c] = p4[(size_t)c * (HWn / 4)];

    int4 y4 = t4[tid];
    int ys[4] = {y4.x, y4.y, y4.z, y4.w};
    float smy[4];
    #pragma unroll
    for (int k = 0; k < 4; ++k) smy[k] = s_sm[ys[k]];

    const float S2 = Sc * LOG2E;

    // pass 1: max + target value (base-2 logits), nothing stored
    float mx[4] = {-1e30f, -1e30f, -1e30f, -1e30f};
    float vy[4] = {0.f, 0.f, 0.f, 0.f};
    #pragma unroll
    for (int c = 0; c < Cc; ++c) {
        float xs[4] = {x[c].x, x[c].y, x[c].z, x[c].w};
        #pragma unroll
        for (int k = 0; k < 4; ++k) {
            bool  isy = (c == ys[k]);
            float val = fmaf(S2, xs[k], isy ? -smy[k] : 0.0f);
            mx[k] = fmaxf(mx[k], val);
            vy[k] = isy ? val : vy[k];
        }
    }

    // pass 2: sum of exp2 recomputed from x
    float nll2 = 0.0f;
    #pragma unroll
    for (int k = 0; k < 4; ++k) {
        float cb = -mx[k];                    // non-target: val - mx
        float cy = -smy[k] - mx[k];           // target: val - mx
        float sum = 0.0f;
        #pragma unroll
        for (int c = 0; c < Cc; ++c) {
            float xs = (k == 0) ? x[c].x : (k == 1) ? x[c].y : (k == 2) ? x[c].z : x[c].w;
            sum += exp2f(fmaf(S2, xs, (c == ys[k]) ? cy : cb));
        }
        nll2 += __log2f(sum) + mx[k] - vy[k];
    }
    float nll = nll2 * LN2;

    // wave (64-lane) reduce
    #pragma unroll
    for (int o = 32; o >= 1; o >>= 1) nll += __shfl_down(nll, o);

    int wave = t >> 6;
    int lane = t & 63;
    if (lane == 0) wsum[wave] = nll;
    __syncthreads();
    if (t == 0) {
        float bsum = wsum[0] + wsum[1] + wsum[2] + wsum[3];
        atomicAdd(acc, (double)bsum);
        __threadfence();                      // release: acc add visible first
        int prev = atomicAdd(loss_done, 1);
        if (prev == (int)gridDim.x - 1) {     // last block finalizes
            __threadfence();                  // acquire
            double total = atomicAdd(acc, 0.0);  // device-scope atomic read
            out[0] = (float)(total / (double)Nn);
        }
    }
}

extern "C" void kernel_launch(void* const* d_in, const int* in_sizes, int n_in,
                              void* d_out, int out_size, void* d_ws, size_t ws_size,
                              hipStream_t stream) {
    const float* pred   = (const float*)d_in[0];
    const int*   target = (const int*)d_in[1];
    float*       out    = (float*)d_out;

    char* ws = (char*)d_ws;
    int*    counts    = (int*)(ws + WS_COUNTS);
    int*    hist_done = (int*)(ws + WS_HIST_DONE);
    int*    loss_done = (int*)(ws + WS_LOSS_DONE);
    double* acc       = (double*)(ws + WS_ACC);
    float*  sm        = (float*)(ws + WS_SM);

    hipMemsetAsync(d_ws, 0, 256, stream);     // zero counts/done/acc/sm

    hist_kernel<<<Nn / 8 / 256, 256, 0, stream>>>((const int4*)target, counts,
                                                  hist_done, sm);
    loss_kernel<<<Nn / 4 / 256, 256, 0, stream>>>(pred, (const int4*)target, sm,
                                                  acc, loss_done, out);
}

// Round 7
// 273.215 us; speedup vs baseline: 1.4107x; 1.4107x over previous
//
#include <hip/hip_runtime.h>

// Problem constants
static constexpr int   Cc  = 21;
static constexpr int   HWn = 512 * 512;         // 262144 = 2^18
static constexpr int   Nn  = 8 * HWn;           // 2097152 pixels
static constexpr float MAXM  = 0.5f;
static constexpr float Sc    = 30.0f;
static constexpr float LOG2E = 1.4426950408889634f;
static constexpr float LN2   = 0.6931471805599453f;

// ws layout (bytes), zeroed by one 256-B memsetAsync:
//   0: int counts[21] ; 88: int hist_done ; 96: double acc ; 128: float sm2[21]
static constexpr int WS_COUNTS    = 0;
static constexpr int WS_HIST_DONE = 88;
static constexpr int WS_ACC       = 96;
static constexpr int WS_SM        = 128;

// ---------------------------------------------------------------------------
// K1: class histogram (8 labels/thread, per-wave LDS sub-histograms) + fused
// m_list: last block computes sm2[c] = S*LOG2E*m_list[c] from global counts.
// NO __threadfence (R6 lesson: device-scope release fence = L2 writeback,
// expensive): ordering comes from __syncthreads() draining the count atomics
// before the done atomic, and counts are read back with device-scope atomics.
__global__ __launch_bounds__(256) void hist_kernel(const int4* __restrict__ t4,
                                                   int* __restrict__ counts,
                                                   int* __restrict__ hist_done,
                                                   float* __restrict__ sm2) {
    __shared__ int lh[4][Cc];                 // per-wave sub-histograms
    __shared__ int is_last;
    int t    = threadIdx.x;
    int wave = t >> 6;
    if (t < Cc) { lh[0][t] = 0; lh[1][t] = 0; lh[2][t] = 0; lh[3][t] = 0; }
    __syncthreads();

    int tid = blockIdx.x * 256 + t;           // [0, Nn/8)
    int4 a = t4[tid];
    int4 b = t4[tid + (Nn / 8)];
    atomicAdd(&lh[wave][a.x], 1);
    atomicAdd(&lh[wave][a.y], 1);
    atomicAdd(&lh[wave][a.z], 1);
    atomicAdd(&lh[wave][a.w], 1);
    atomicAdd(&lh[wave][b.x], 1);
    atomicAdd(&lh[wave][b.y], 1);
    atomicAdd(&lh[wave][b.z], 1);
    atomicAdd(&lh[wave][b.w], 1);
    __syncthreads();
    if (t < Cc) atomicAdd(&counts[t], lh[0][t] + lh[1][t] + lh[2][t] + lh[3][t]);
    __syncthreads();                          // drains count atomics (vmcnt)

    if (t == 0) is_last = (atomicAdd(hist_done, 1) == (int)gridDim.x - 1);
    __syncthreads();

    if (is_last && t < 64) {                  // fused mlist on one wave
        float mval = 0.0f;
        if (t < Cc) {
            int cnt = atomicAdd(&counts[t], 0);   // device-scope atomic read
            mval = 1.0f / sqrtf(sqrtf((float)cnt + 1e-4f));
        }
        float mx = mval;
        #pragma unroll
        for (int o = 32; o >= 1; o >>= 1) mx = fmaxf(mx, __shfl_down(mx, o));
        mx = __shfl(mx, 0);
        if (t < Cc) sm2[t] = Sc * LOG2E * mval * (MAXM / mx);
    }
}

// ---------------------------------------------------------------------------
// K2: main loss — BYTE-IDENTICAL to the round-5 fast version. GOLDEN: every
// modification of this kernel (online lse, fused finalize, threadfence) has
// regressed 4x via load-stream serialization. Do not touch.
__global__ __launch_bounds__(256, 2) void loss_kernel(const float* __restrict__ pred,
                                                      const int4* __restrict__ t4,
                                                      const float* __restrict__ smg,
                                                      double* __restrict__ acc) {
    __shared__ float s_sm[Cc];
    __shared__ float wsum[4];
    int t = threadIdx.x;
    if (t < Cc) s_sm[t] = smg[t];
    __syncthreads();

    int tid = blockIdx.x * 256 + t;           // tid in [0, Nn/4)
    int n0  = tid * 4;
    int b   = n0 >> 18;                       // HWn = 2^18
    int hw  = n0 & (HWn - 1);
    const float4* p4 = (const float4*)(pred + (size_t)b * Cc * HWn + hw);

    // issue all 21 coalesced float4 loads back-to-back (MLP)
    float4 x[Cc];
    #pragma unroll
    for (int c = 0; c < Cc; ++c) x[c] = p4[(size_t)c * (HWn / 4)];

    int4 y4 = t4[tid];
    int ys[4] = {y4.x, y4.y, y4.z, y4.w};
    float smy[4];
    #pragma unroll
    for (int k = 0; k < 4; ++k) smy[k] = s_sm[ys[k]];

    const float S2 = Sc * LOG2E;

    // pass 1: max + target value (base-2 logits), nothing stored
    float mx[4] = {-1e30f, -1e30f, -1e30f, -1e30f};
    float vy[4] = {0.f, 0.f, 0.f, 0.f};
    #pragma unroll
    for (int c = 0; c < Cc; ++c) {
        float xs[4] = {x[c].x, x[c].y, x[c].z, x[c].w};
        #pragma unroll
        for (int k = 0; k < 4; ++k) {
            bool  isy = (c == ys[k]);
            float val = fmaf(S2, xs[k], isy ? -smy[k] : 0.0f);
            mx[k] = fmaxf(mx[k], val);
            vy[k] = isy ? val : vy[k];
        }
    }

    // pass 2: sum of exp2 recomputed from x
    float nll2 = 0.0f;
    #pragma unroll
    for (int k = 0; k < 4; ++k) {
        float cb = -mx[k];                    // non-target: val - mx
        float cy = -smy[k] - mx[k];           // target: val - mx
        float sum = 0.0f;
        #pragma unroll
        for (int c = 0; c < Cc; ++c) {
            float xs = (k == 0) ? x[c].x : (k == 1) ? x[c].y : (k == 2) ? x[c].z : x[c].w;
            sum += exp2f(fmaf(S2, xs, (c == ys[k]) ? cy : cb));
        }
        nll2 += __log2f(sum) + mx[k] - vy[k];
    }
    float nll = nll2 * LN2;

    // wave (64-lane) reduce
    #pragma unroll
    for (int o = 32; o >= 1; o >>= 1) nll += __shfl_down(nll, o);

    int wave = t >> 6;
    int lane = t & 63;
    if (lane == 0) wsum[wave] = nll;
    __syncthreads();
    if (t == 0) {
        float bsum = wsum[0] + wsum[1] + wsum[2] + wsum[3];
        atomicAdd(acc, (double)bsum);
    }
}

// ---------------------------------------------------------------------------
// K3: finalize mean (kernel boundary provides ordering/coherence for acc).
__global__ void final_kernel(const double* __restrict__ acc, float* __restrict__ out) {
    out[0] = (float)(acc[0] / (double)Nn);
}

extern "C" void kernel_launch(void* const* d_in, const int* in_sizes, int n_in,
                              void* d_out, int out_size, void* d_ws, size_t ws_size,
                              hipStream_t stream) {
    const float* pred   = (const float*)d_in[0];
    const int*   target = (const int*)d_in[1];
    float*       out    = (float*)d_out;

    char* ws = (char*)d_ws;
    int*    counts    = (int*)(ws + WS_COUNTS);
    int*    hist_done = (int*)(ws + WS_HIST_DONE);
    double* acc       = (double*)(ws + WS_ACC);
    float*  sm        = (float*)(ws + WS_SM);

    hipMemsetAsync(d_ws, 0, 256, stream);     // zero counts/done/acc/sm

    hist_kernel <<<Nn / 8 / 256, 256, 0, stream>>>((const int4*)target, counts,
                                                   hist_done, sm);
    loss_kernel <<<Nn / 4 / 256, 256, 0, stream>>>(pred, (const int4*)target, sm, acc);
    final_kernel<<<1,            1,   0, stream>>>(acc, out);
}